// Round 1
// baseline (779.600 us; speedup 1.0000x reference)
//
#include <hip/hip_runtime.h>
#include <math.h>

namespace {
constexpr int NN  = 16384;
constexpr int NE  = 262144;
constexpr int DIM = 40;

constexpr float INV_SQRT3   = 0.5773502691896258f;
constexpr float A_PATH      = 0.2041241452319315f;      // 1/sqrt(16+8)
constexpr float INV_SQRT_NB = 0.31622776601683794f;     // 1/sqrt(10)
constexpr float H_SCALE     = 0.25f;                    // 1/sqrt(RH=16), folded into h
constexpr float QSC_S       = 0.25f;                    // 1/sqrt(16)
constexpr float QV_S        = 0.35355339059327373f;     // 1/sqrt(8)
constexpr float D00_S       = 1.0f / (16.0f * 1.4142135623730951f);
constexpr float D11_S       = 1.0f / (8.0f * 1.7320508075688772f * 1.4142135623730951f);
constexpr float MAX_RADIUS  = 1.3f;
}

// Precompute per-node "query-dot" vector: qd[n][0..15] = (q_sc @ Wd00)/(16*sqrt2),
// qd[n][16 + j*3 + c] = (q_vec[:,c] @ Wd11)/(8*sqrt3*sqrt2).
// Then per-edge score s = sum_j qd[dst][j] * k_flat[j].
__global__ __launch_bounds__(256) void node_q_kernel(
    const float* __restrict__ f,
    const float* __restrict__ Wq0, const float* __restrict__ Wq1,
    const float* __restrict__ Wd00, const float* __restrict__ Wd11,
    float* __restrict__ qd)
{
  int n = blockIdx.x * 256 + threadIdx.x;
  const float* fn = f + (size_t)n * DIM;
  float fs[16], fv[8][3];
#pragma unroll
  for (int i = 0; i < 10; i++) {
    float4 t = reinterpret_cast<const float4*>(fn)[i];
    float* d = (i < 4) ? nullptr : nullptr; (void)d;
    int base = i * 4;
#pragma unroll
    for (int k = 0; k < 4; k++) {
      float v = (k == 0) ? t.x : (k == 1) ? t.y : (k == 2) ? t.z : t.w;
      int idx = base + k;
      if (idx < 16) fs[idx] = v;
      else { int r = idx - 16; fv[r / 3][r % 3] = v; }
    }
  }

  float qsc[16];
#pragma unroll
  for (int o = 0; o < 16; o++) {
    float a = 0.f;
#pragma unroll
    for (int i = 0; i < 16; i++) a += fs[i] * Wq0[i * 16 + o];
    qsc[o] = a * QSC_S;
  }
  float qv[8][3];
#pragma unroll
  for (int o = 0; o < 8; o++)
#pragma unroll
    for (int c = 0; c < 3; c++) {
      float a = 0.f;
#pragma unroll
      for (int i = 0; i < 8; i++) a += fv[i][c] * Wq1[i * 8 + o];
      qv[o][c] = a * QV_S;
    }

  float* out = qd + (size_t)n * DIM;
#pragma unroll
  for (int j = 0; j < 16; j++) {
    float a = 0.f;
#pragma unroll
    for (int i = 0; i < 16; i++) a += qsc[i] * Wd00[i * 16 + j];
    out[j] = a * D00_S;
  }
#pragma unroll
  for (int j = 0; j < 8; j++)
#pragma unroll
    for (int c = 0; c < 3; c++) {
      float a = 0.f;
#pragma unroll
      for (int i = 0; i < 8; i++) a += qv[i][c] * Wd11[i * 8 + j];
      out[16 + j * 3 + c] = a * D11_S;
    }
}

// PASS 0: K-pass (node = dst, weights fck): compute exp_ijk, atomicAdd z[dst].
// PASS 1: V-pass (node = src, weights fcv): compute v, scale by sqrt(exp/z), atomicAdd f_out[dst].
template <int PASS>
__global__ __launch_bounds__(256) void edge_kernel(
    const int*   __restrict__ edge_index,
    const float* __restrict__ edge_length,
    const float* __restrict__ edge_sh,
    const float* __restrict__ emb,
    const float* __restrict__ w1,    // (10,16)
    const float* __restrict__ w2,    // (16,576)
    const float* __restrict__ f,
    const float* __restrict__ qd,
    float* __restrict__ expv,
    float* __restrict__ z,
    float* __restrict__ fout)
{
  __shared__ float h_lds[256][17];   // padded stride -> conflict-free dynamic r reads
  const int tid = threadIdx.x;
  const int e = blockIdx.x * 256 + tid;

  const int src = edge_index[e];
  const int dst = edge_index[NE + e];
  const int node = (PASS == 0) ? dst : src;

  // ---- radial hidden h (folds 1/sqrt(RH) in) ----
  {
    float el[10];
    const float2* e2 = reinterpret_cast<const float2*>(emb + (size_t)e * 10);
#pragma unroll
    for (int b = 0; b < 5; b++) { float2 t = e2[b]; el[2 * b] = t.x; el[2 * b + 1] = t.y; }
#pragma unroll
    for (int j = 0; j < 16; j++) {
      float a = 0.f;
#pragma unroll
      for (int b = 0; b < 10; b++) a += el[b] * w1[b * 16 + j];
      a *= INV_SQRT_NB;
      float sig = 1.0f / (1.0f + __expf(-a));
      h_lds[tid][j] = a * sig * H_SCALE;
    }
  }

  // ---- gather node features ----
  float fs[16], fv[8][3];
  {
    const float4* fn4 = reinterpret_cast<const float4*>(f + (size_t)node * DIM);
#pragma unroll
    for (int i = 0; i < 10; i++) {
      float4 t = fn4[i];
      int base = i * 4;
#pragma unroll
      for (int k = 0; k < 4; k++) {
        float v = (k == 0) ? t.x : (k == 1) ? t.y : (k == 2) ? t.z : t.w;
        int idx = base + k;
        if (idx < 16) fs[idx] = v;
        else { int r = idx - 16; fv[r / 3][r % 3] = v; }
      }
    }
  }

  float4 sh4 = reinterpret_cast<const float4*>(edge_sh)[e];
  const float sh0 = sh4.x;
  const float shv0 = sh4.y, shv1 = sh4.z, shv2 = sh4.w;

  // fss folds sh_sc into the w00 path; fvp folds INV_SQRT3 * (sh_vec . f_vec) for w11.
  float fss[16];
#pragma unroll
  for (int i = 0; i < 16; i++) fss[i] = fs[i] * sh0;
  float fvp[8];
#pragma unroll
  for (int i = 0; i < 8; i++)
    fvp[i] = INV_SQRT3 * (fv[i][0] * shv0 + fv[i][1] * shv1 + fv[i][2] * shv2);

  float acc_sc[16], acc01[8], accv[8][3];
#pragma unroll
  for (int o = 0; o < 16; o++) acc_sc[o] = 0.f;
#pragma unroll
  for (int o = 0; o < 8; o++) acc01[o] = 0.f;
#pragma unroll
  for (int o = 0; o < 8; o++)
#pragma unroll
    for (int c = 0; c < 3; c++) accv[o][c] = 0.f;

  // ---- main fused radial@w2 + tensor-product contraction ----
#pragma unroll 1
  for (int r = 0; r < 16; r++) {
    const float hr = h_lds[tid][r];
    const float4* __restrict__ w2r4 = reinterpret_cast<const float4*>(w2 + (size_t)r * 576);

    // w00 block: cols [0,256): acc_sc[o] += hr*fss[i]*w2[r, i*16+o]
#pragma unroll
    for (int i = 0; i < 16; i++) {
      const float t = hr * fss[i];
#pragma unroll
      for (int o4 = 0; o4 < 4; o4++) {
        float4 w = w2r4[i * 4 + o4];
        acc_sc[o4 * 4 + 0] += t * w.x;
        acc_sc[o4 * 4 + 1] += t * w.y;
        acc_sc[o4 * 4 + 2] += t * w.z;
        acc_sc[o4 * 4 + 3] += t * w.w;
      }
    }
    // w11 block: cols [256,384): acc_sc[o] += hr*fvp[i]*w2[r, 256+i*16+o]
#pragma unroll
    for (int i = 0; i < 8; i++) {
      const float t = hr * fvp[i];
#pragma unroll
      for (int o4 = 0; o4 < 4; o4++) {
        float4 w = w2r4[64 + i * 4 + o4];
        acc_sc[o4 * 4 + 0] += t * w.x;
        acc_sc[o4 * 4 + 1] += t * w.y;
        acc_sc[o4 * 4 + 2] += t * w.z;
        acc_sc[o4 * 4 + 3] += t * w.w;
      }
    }
    // w01 block: cols [384,512): acc01[o] += hr*fs[i]*w2[r, 384+i*8+o]
#pragma unroll
    for (int i = 0; i < 16; i++) {
      const float t = hr * fs[i];
#pragma unroll
      for (int o4 = 0; o4 < 2; o4++) {
        float4 w = w2r4[96 + i * 2 + o4];
        acc01[o4 * 4 + 0] += t * w.x;
        acc01[o4 * 4 + 1] += t * w.y;
        acc01[o4 * 4 + 2] += t * w.z;
        acc01[o4 * 4 + 3] += t * w.w;
      }
    }
    // w10 block: cols [512,576): accv[o][c] += hr*fv[i][c]*w2[r, 512+i*8+o]
#pragma unroll
    for (int i = 0; i < 8; i++) {
      const float t0 = hr * fv[i][0];
      const float t1 = hr * fv[i][1];
      const float t2 = hr * fv[i][2];
#pragma unroll
      for (int o4 = 0; o4 < 2; o4++) {
        float4 w = w2r4[128 + i * 2 + o4];
#pragma unroll
        for (int k = 0; k < 4; k++) {
          float wk = (k == 0) ? w.x : (k == 1) ? w.y : (k == 2) ? w.z : w.w;
          int o = o4 * 4 + k;
          accv[o][0] += t0 * wk;
          accv[o][1] += t1 * wk;
          accv[o][2] += t2 * wk;
        }
      }
    }
  }

  if (PASS == 0) {
    // score s = qd[dst] . k_flat
    const float* qdn = qd + (size_t)dst * DIM;
    float s = 0.f;
#pragma unroll
    for (int j = 0; j < 16; j++) s += qdn[j] * (A_PATH * acc_sc[j]);
#pragma unroll
    for (int j = 0; j < 8; j++) {
      float kv0 = A_PATH * (shv0 * acc01[j] + sh0 * accv[j][0]);
      float kv1 = A_PATH * (shv1 * acc01[j] + sh0 * accv[j][1]);
      float kv2 = A_PATH * (shv2 * acc01[j] + sh0 * accv[j][2]);
      s += qdn[16 + j * 3 + 0] * kv0 + qdn[16 + j * 3 + 1] * kv1 + qdn[16 + j * 3 + 2] * kv2;
    }
    float len = edge_length[e];
    float x = 10.0f * (1.0f - len * (1.0f / MAX_RADIUS));
    float cut = (x > 0.f) ? __expf(-1.0f / x) : 0.f;
    float ev = cut * __expf(s);
    expv[e] = ev;
    atomicAdd(&z[dst], ev);
  } else {
    float zz = z[dst];
    zz = (zz == 0.f) ? 1.0f : zz;
    float ev = expv[e];
    float al = ev / zz;
    float w = sqrtf(fmaxf(al, 0.f));
    float* fo = fout + (size_t)dst * DIM;
#pragma unroll
    for (int o = 0; o < 16; o++) atomicAdd(&fo[o], w * A_PATH * acc_sc[o]);
#pragma unroll
    for (int o = 0; o < 8; o++) {
      atomicAdd(&fo[16 + o * 3 + 0], w * A_PATH * (shv0 * acc01[o] + sh0 * accv[o][0]));
      atomicAdd(&fo[16 + o * 3 + 1], w * A_PATH * (shv1 * acc01[o] + sh0 * accv[o][1]));
      atomicAdd(&fo[16 + o * 3 + 2], w * A_PATH * (shv2 * acc01[o] + sh0 * accv[o][2]));
    }
  }
}

extern "C" void kernel_launch(void* const* d_in, const int* in_sizes, int n_in,
                              void* d_out, int out_size, void* d_ws, size_t ws_size,
                              hipStream_t stream) {
  const float* f      = (const float*)d_in[0];
  const int*   ei     = (const int*)d_in[1];
  const float* elen   = (const float*)d_in[2];
  const float* esh    = (const float*)d_in[3];
  const float* emb    = (const float*)d_in[4];
  const float* Wq0    = (const float*)d_in[5];
  const float* Wq1    = (const float*)d_in[6];
  const float* fck_w1 = (const float*)d_in[7];
  const float* fck_w2 = (const float*)d_in[8];
  const float* fcv_w1 = (const float*)d_in[9];
  const float* fcv_w2 = (const float*)d_in[10];
  const float* Wd00   = (const float*)d_in[11];
  const float* Wd11   = (const float*)d_in[12];

  float* out  = (float*)d_out;
  float* qd   = (float*)d_ws;            // NN*DIM
  float* z    = qd + (size_t)NN * DIM;   // NN
  float* expv = z + NN;                  // NE

  hipMemsetAsync(z, 0, NN * sizeof(float), stream);
  hipMemsetAsync(out, 0, (size_t)NN * DIM * sizeof(float), stream);

  node_q_kernel<<<NN / 256, 256, 0, stream>>>(f, Wq0, Wq1, Wd00, Wd11, qd);
  edge_kernel<0><<<NE / 256, 256, 0, stream>>>(ei, elen, esh, emb, fck_w1, fck_w2,
                                               f, qd, expv, z, out);
  edge_kernel<1><<<NE / 256, 256, 0, stream>>>(ei, elen, esh, emb, fcv_w1, fcv_w2,
                                               f, qd, expv, z, out);
}

// Round 2
// 249.072 us; speedup vs baseline: 3.1300x; 3.1300x over previous
//
#include <hip/hip_runtime.h>
#include <math.h>

namespace {
constexpr int NN  = 16384;
constexpr int NE  = 262144;
constexpr int DIM = 40;

constexpr float INV_SQRT3   = 0.5773502691896258f;
constexpr float A_PATH      = 0.2041241452319315f;      // 1/sqrt(24)
constexpr float INV_SQRT_NB = 0.31622776601683794f;     // 1/sqrt(10)
constexpr float H_SCALE     = 0.25f;                    // 1/sqrt(16)
constexpr float QSC_S       = 0.25f;
constexpr float QV_S        = 0.35355339059327373f;
constexpr float D00_S       = 1.0f / (16.0f * 1.4142135623730951f);
constexpr float D11_S       = 1.0f / (8.0f * 1.7320508075688772f * 1.4142135623730951f);
}

// ---------------------------------------------------------------------------
// Per-node score factorization: qq[n][r][j] such that per-edge score
//   s = sum_r h_r * (sh0*qq[dst][r][0] + sh1*qq[r][1] + sh2*qq[r][2] + sh3*qq[r][3])
// 4 threads per node, each handles 4 radial channels.
// ---------------------------------------------------------------------------
__global__ __launch_bounds__(256) void node_qq_kernel(
    const float* __restrict__ f,
    const float* __restrict__ Wq0, const float* __restrict__ Wq1,
    const float* __restrict__ Wd00, const float* __restrict__ Wd11,
    const float* __restrict__ w2k,
    float* __restrict__ qq)
{
  const int gid = blockIdx.x * 256 + threadIdx.x;
  const int n = gid >> 2, rq = gid & 3;

  float fs[16], fv[8][3];
  {
    const float4* fn4 = reinterpret_cast<const float4*>(f + (size_t)n * DIM);
#pragma unroll
    for (int i = 0; i < 10; i++) {
      float4 t = fn4[i];
      int base = i * 4;
#pragma unroll
      for (int k = 0; k < 4; k++) {
        float v = (k == 0) ? t.x : (k == 1) ? t.y : (k == 2) ? t.z : t.w;
        int idx = base + k;
        if (idx < 16) fs[idx] = v;
        else { int r = idx - 16; fv[r / 3][r % 3] = v; }
      }
    }
  }

  // q = f @ Wq, then qd = q @ Wd (with all scales folded)
  float qd0[16];
  {
    float qsc[16];
#pragma unroll
    for (int o = 0; o < 16; o++) {
      float a = 0.f;
#pragma unroll
      for (int i = 0; i < 16; i++) a += fs[i] * Wq0[i * 16 + o];
      qsc[o] = a * QSC_S;
    }
#pragma unroll
    for (int j = 0; j < 16; j++) {
      float a = 0.f;
#pragma unroll
      for (int i = 0; i < 16; i++) a += qsc[i] * Wd00[i * 16 + j];
      qd0[j] = a * D00_S;
    }
  }
  float qdv[8][3];
  {
    float qv[8][3];
#pragma unroll
    for (int o = 0; o < 8; o++)
#pragma unroll
      for (int c = 0; c < 3; c++) {
        float a = 0.f;
#pragma unroll
        for (int i = 0; i < 8; i++) a += fv[i][c] * Wq1[i * 8 + o];
        qv[o][c] = a * QV_S;
      }
#pragma unroll
    for (int j = 0; j < 8; j++)
#pragma unroll
      for (int c = 0; c < 3; c++) {
        float a = 0.f;
#pragma unroll
        for (int i = 0; i < 8; i++) a += qv[i][c] * Wd11[i * 8 + j];
        qdv[j][c] = a * D11_S;
      }
  }

#pragma unroll 1
  for (int rr = 0; rr < 4; rr++) {
    const int r = rq * 4 + rr;
    const float4* __restrict__ w4 = reinterpret_cast<const float4*>(w2k + (size_t)r * 576);
    float q0 = 0.f, qc0 = 0.f, qc1 = 0.f, qc2 = 0.f;

    // w00 block [0,256): couples f_sc with qd0, sh0
#pragma unroll
    for (int i = 0; i < 16; i++) {
      float t = 0.f;
#pragma unroll
      for (int o4 = 0; o4 < 4; o4++) {
        float4 w = w4[i * 4 + o4];
        t += qd0[o4 * 4 + 0] * w.x + qd0[o4 * 4 + 1] * w.y
           + qd0[o4 * 4 + 2] * w.z + qd0[o4 * 4 + 3] * w.w;
      }
      q0 += fs[i] * t;
    }
    // w11 block [256,384): couples f_vec[:,c] with qd0, sh_c, INV_SQRT3
#pragma unroll
    for (int i = 0; i < 8; i++) {
      float t = 0.f;
#pragma unroll
      for (int o4 = 0; o4 < 4; o4++) {
        float4 w = w4[64 + i * 4 + o4];
        t += qd0[o4 * 4 + 0] * w.x + qd0[o4 * 4 + 1] * w.y
           + qd0[o4 * 4 + 2] * w.z + qd0[o4 * 4 + 3] * w.w;
      }
      t *= INV_SQRT3;
      qc0 += fv[i][0] * t; qc1 += fv[i][1] * t; qc2 += fv[i][2] * t;
    }
    // w01 block [384,512): couples f_sc with qdv[:,c], sh_c
#pragma unroll
    for (int i = 0; i < 16; i++) {
      float t0 = 0.f, t1 = 0.f, t2 = 0.f;
#pragma unroll
      for (int o4 = 0; o4 < 2; o4++) {
        float4 w = w4[96 + i * 2 + o4];
#pragma unroll
        for (int k = 0; k < 4; k++) {
          float wk = (k == 0) ? w.x : (k == 1) ? w.y : (k == 2) ? w.z : w.w;
          int o = o4 * 4 + k;
          t0 += qdv[o][0] * wk; t1 += qdv[o][1] * wk; t2 += qdv[o][2] * wk;
        }
      }
      qc0 += fs[i] * t0; qc1 += fs[i] * t1; qc2 += fs[i] * t2;
    }
    // w10 block [512,576): couples f_vec[:,c] with qdv[:,c], sh0
#pragma unroll
    for (int i = 0; i < 8; i++) {
      float t0 = 0.f, t1 = 0.f, t2 = 0.f;
#pragma unroll
      for (int o4 = 0; o4 < 2; o4++) {
        float4 w = w4[128 + i * 2 + o4];
#pragma unroll
        for (int k = 0; k < 4; k++) {
          float wk = (k == 0) ? w.x : (k == 1) ? w.y : (k == 2) ? w.z : w.w;
          int o = o4 * 4 + k;
          t0 += qdv[o][0] * wk; t1 += qdv[o][1] * wk; t2 += qdv[o][2] * wk;
        }
      }
      q0 += fv[i][0] * t0 + fv[i][1] * t1 + fv[i][2] * t2;
    }

    float4 outv = make_float4(A_PATH * q0, A_PATH * qc0, A_PATH * qc1, A_PATH * qc2);
    reinterpret_cast<float4*>(qq + ((size_t)n * 16 + r) * 4)[0] = outv;
  }
}

// ---------------------------------------------------------------------------
// K-pass: per-edge score via qq factorization. ~250 MACs/edge.
// ---------------------------------------------------------------------------
__global__ __launch_bounds__(256) void k_pass_kernel(
    const int*   __restrict__ ei,
    const float* __restrict__ elen,
    const float* __restrict__ esh,
    const float* __restrict__ emb,
    const float* __restrict__ w1,     // fck_w1 (10,16)
    const float* __restrict__ qq,
    float* __restrict__ expv,
    float* __restrict__ z)
{
  const int e = blockIdx.x * 256 + threadIdx.x;
  const int dst = ei[NE + e];

  float el[10];
  const float2* e2 = reinterpret_cast<const float2*>(emb + (size_t)e * 10);
#pragma unroll
  for (int b = 0; b < 5; b++) { float2 t = e2[b]; el[2 * b] = t.x; el[2 * b + 1] = t.y; }

  float h[16];
#pragma unroll
  for (int j = 0; j < 16; j++) {
    float a = 0.f;
#pragma unroll
    for (int b = 0; b < 10; b++) a += el[b] * w1[b * 16 + j];
    a *= INV_SQRT_NB;
    float sig = 1.0f / (1.0f + __expf(-a));
    h[j] = a * sig * H_SCALE;
  }

  float4 sh4 = reinterpret_cast<const float4*>(esh)[e];
  const float4* q4 = reinterpret_cast<const float4*>(qq + (size_t)dst * 64);
  float s = 0.f;
#pragma unroll
  for (int r = 0; r < 16; r++) {
    float4 qv = q4[r];
    s += h[r] * (sh4.x * qv.x + sh4.y * qv.y + sh4.z * qv.z + sh4.w * qv.w);
  }

  float len = elen[e];
  float x = 10.0f * (1.0f - len * (1.0f / 1.3f));
  float cut = (x > 0.f) ? __expf(-1.0f / x) : 0.f;
  float ev = cut * __expf(s);
  expv[e] = ev;
  atomicAdd(&z[dst], ev);
}

// ---------------------------------------------------------------------------
// Counting sort by dst: histogram -> scan -> scatter (rank per edge)
// ---------------------------------------------------------------------------
__global__ __launch_bounds__(256) void hist_kernel(const int* __restrict__ ei,
                                                   int* __restrict__ cnt)
{
  const int e = blockIdx.x * 256 + threadIdx.x;
  atomicAdd(&cnt[ei[NE + e]], 1);
}

__global__ __launch_bounds__(1024) void scan_kernel(const int* __restrict__ cnt,
                                                    int* __restrict__ start,
                                                    int* __restrict__ off)
{
  __shared__ int part[1024];
  const int t = threadIdx.x;
  const int base = t * 16;
  int loc[16];
  int s = 0;
#pragma unroll
  for (int k = 0; k < 16; k++) { loc[k] = s; s += cnt[base + k]; }
  part[t] = s;
  __syncthreads();
  for (int d = 1; d < 1024; d <<= 1) {
    int v = (t >= d) ? part[t - d] : 0;
    __syncthreads();
    part[t] += v;
    __syncthreads();
  }
  int excl = (t == 0) ? 0 : part[t - 1];
#pragma unroll
  for (int k = 0; k < 16; k++) {
    int v = excl + loc[k];
    start[base + k] = v;
    off[base + k] = v;
  }
}

__global__ __launch_bounds__(256) void scatter_kernel(const int* __restrict__ ei,
                                                      int* __restrict__ off,
                                                      int* __restrict__ rank)
{
  const int e = blockIdx.x * 256 + threadIdx.x;
  rank[e] = atomicAdd(&off[ei[NE + e]], 1);
}

// ---------------------------------------------------------------------------
// V-pass: full TP with fcv weights at src node, scaled by sqrt(alpha),
// written to vbuf[rank[e]] (no atomics).
// ---------------------------------------------------------------------------
__global__ __launch_bounds__(256) void v_pass_kernel(
    const int*   __restrict__ ei,
    const float* __restrict__ esh,
    const float* __restrict__ emb,
    const float* __restrict__ w1,    // fcv_w1
    const float* __restrict__ w2,    // fcv_w2
    const float* __restrict__ f,
    const float* __restrict__ expv,
    const float* __restrict__ z,
    const int*   __restrict__ rank,
    float* __restrict__ vbuf)
{
  __shared__ float h_lds[256][17];
  const int tid = threadIdx.x;
  const int e = blockIdx.x * 256 + tid;

  const int src = ei[e];
  const int dst = ei[NE + e];

  {
    float el[10];
    const float2* e2 = reinterpret_cast<const float2*>(emb + (size_t)e * 10);
#pragma unroll
    for (int b = 0; b < 5; b++) { float2 t = e2[b]; el[2 * b] = t.x; el[2 * b + 1] = t.y; }
#pragma unroll
    for (int j = 0; j < 16; j++) {
      float a = 0.f;
#pragma unroll
      for (int b = 0; b < 10; b++) a += el[b] * w1[b * 16 + j];
      a *= INV_SQRT_NB;
      float sig = 1.0f / (1.0f + __expf(-a));
      h_lds[tid][j] = a * sig * H_SCALE;
    }
  }

  float fs[16], fv[8][3];
  {
    const float4* fn4 = reinterpret_cast<const float4*>(f + (size_t)src * DIM);
#pragma unroll
    for (int i = 0; i < 10; i++) {
      float4 t = fn4[i];
      int base = i * 4;
#pragma unroll
      for (int k = 0; k < 4; k++) {
        float v = (k == 0) ? t.x : (k == 1) ? t.y : (k == 2) ? t.z : t.w;
        int idx = base + k;
        if (idx < 16) fs[idx] = v;
        else { int r = idx - 16; fv[r / 3][r % 3] = v; }
      }
    }
  }

  float4 sh4 = reinterpret_cast<const float4*>(esh)[e];
  const float sh0 = sh4.x, shv0 = sh4.y, shv1 = sh4.z, shv2 = sh4.w;

  float fss[16];
#pragma unroll
  for (int i = 0; i < 16; i++) fss[i] = fs[i] * sh0;
  float fvp[8];
#pragma unroll
  for (int i = 0; i < 8; i++)
    fvp[i] = INV_SQRT3 * (fv[i][0] * shv0 + fv[i][1] * shv1 + fv[i][2] * shv2);

  float acc_sc[16], acc01[8], accv[8][3];
#pragma unroll
  for (int o = 0; o < 16; o++) acc_sc[o] = 0.f;
#pragma unroll
  for (int o = 0; o < 8; o++) acc01[o] = 0.f;
#pragma unroll
  for (int o = 0; o < 8; o++)
#pragma unroll
    for (int c = 0; c < 3; c++) accv[o][c] = 0.f;

#pragma unroll 1
  for (int r = 0; r < 16; r++) {
    const float hr = h_lds[tid][r];
    const float4* __restrict__ w2r4 = reinterpret_cast<const float4*>(w2 + (size_t)r * 576);

#pragma unroll
    for (int i = 0; i < 16; i++) {
      const float t = hr * fss[i];
#pragma unroll
      for (int o4 = 0; o4 < 4; o4++) {
        float4 w = w2r4[i * 4 + o4];
        acc_sc[o4 * 4 + 0] += t * w.x;
        acc_sc[o4 * 4 + 1] += t * w.y;
        acc_sc[o4 * 4 + 2] += t * w.z;
        acc_sc[o4 * 4 + 3] += t * w.w;
      }
    }
#pragma unroll
    for (int i = 0; i < 8; i++) {
      const float t = hr * fvp[i];
#pragma unroll
      for (int o4 = 0; o4 < 4; o4++) {
        float4 w = w2r4[64 + i * 4 + o4];
        acc_sc[o4 * 4 + 0] += t * w.x;
        acc_sc[o4 * 4 + 1] += t * w.y;
        acc_sc[o4 * 4 + 2] += t * w.z;
        acc_sc[o4 * 4 + 3] += t * w.w;
      }
    }
#pragma unroll
    for (int i = 0; i < 16; i++) {
      const float t = hr * fs[i];
#pragma unroll
      for (int o4 = 0; o4 < 2; o4++) {
        float4 w = w2r4[96 + i * 2 + o4];
        acc01[o4 * 4 + 0] += t * w.x;
        acc01[o4 * 4 + 1] += t * w.y;
        acc01[o4 * 4 + 2] += t * w.z;
        acc01[o4 * 4 + 3] += t * w.w;
      }
    }
#pragma unroll
    for (int i = 0; i < 8; i++) {
      const float t0 = hr * fv[i][0];
      const float t1 = hr * fv[i][1];
      const float t2 = hr * fv[i][2];
#pragma unroll
      for (int o4 = 0; o4 < 2; o4++) {
        float4 w = w2r4[128 + i * 2 + o4];
#pragma unroll
        for (int k = 0; k < 4; k++) {
          float wk = (k == 0) ? w.x : (k == 1) ? w.y : (k == 2) ? w.z : w.w;
          int o = o4 * 4 + k;
          accv[o][0] += t0 * wk;
          accv[o][1] += t1 * wk;
          accv[o][2] += t2 * wk;
        }
      }
    }
  }

  float zz = z[dst];
  zz = (zz == 0.f) ? 1.0f : zz;
  float ev = expv[e];
  float w = sqrtf(fmaxf(ev / zz, 0.f)) * A_PATH;

  float row[40];
#pragma unroll
  for (int o = 0; o < 16; o++) row[o] = w * acc_sc[o];
#pragma unroll
  for (int o = 0; o < 8; o++) {
    row[16 + o * 3 + 0] = w * (shv0 * acc01[o] + sh0 * accv[o][0]);
    row[16 + o * 3 + 1] = w * (shv1 * acc01[o] + sh0 * accv[o][1]);
    row[16 + o * 3 + 2] = w * (shv2 * acc01[o] + sh0 * accv[o][2]);
  }
  float4* outp = reinterpret_cast<float4*>(vbuf + (size_t)rank[e] * DIM);
#pragma unroll
  for (int q = 0; q < 10; q++)
    outp[q] = make_float4(row[q * 4], row[q * 4 + 1], row[q * 4 + 2], row[q * 4 + 3]);
}

// ---------------------------------------------------------------------------
// Gather: one wave per node, lanes 0..39 own one output each, sum the node's
// contiguous vbuf rows.
// ---------------------------------------------------------------------------
__global__ __launch_bounds__(256) void gather_kernel(
    const float* __restrict__ vbuf,
    const int* __restrict__ start,
    const int* __restrict__ cnt,
    float* __restrict__ fout)
{
  const int tid = threadIdx.x;
  const int node = blockIdx.x * 4 + (tid >> 6);
  const int lane = tid & 63;
  if (lane >= DIM) return;
  const int s0 = start[node];
  const int c = cnt[node];
  float acc = 0.f;
  for (int j = 0; j < c; j++)
    acc += vbuf[(size_t)(s0 + j) * DIM + lane];
  fout[(size_t)node * DIM + lane] = acc;
}

extern "C" void kernel_launch(void* const* d_in, const int* in_sizes, int n_in,
                              void* d_out, int out_size, void* d_ws, size_t ws_size,
                              hipStream_t stream) {
  const float* f      = (const float*)d_in[0];
  const int*   ei     = (const int*)d_in[1];
  const float* elen   = (const float*)d_in[2];
  const float* esh    = (const float*)d_in[3];
  const float* emb    = (const float*)d_in[4];
  const float* Wq0    = (const float*)d_in[5];
  const float* Wq1    = (const float*)d_in[6];
  const float* fck_w1 = (const float*)d_in[7];
  const float* fck_w2 = (const float*)d_in[8];
  const float* fcv_w1 = (const float*)d_in[9];
  const float* fcv_w2 = (const float*)d_in[10];
  const float* Wd00   = (const float*)d_in[11];
  const float* Wd11   = (const float*)d_in[12];

  float* out = (float*)d_out;

  // workspace layout
  char* ws = (char*)d_ws;
  float* qq    = (float*)ws;                 ws += (size_t)NN * 64 * 4;   // 4 MB
  float* z     = (float*)ws;                 ws += (size_t)NN * 4;
  float* expv  = (float*)ws;                 ws += (size_t)NE * 4;        // 1 MB
  int*   cnt   = (int*)ws;                   ws += (size_t)NN * 4;
  int*   startb= (int*)ws;                   ws += (size_t)NN * 4;
  int*   off   = (int*)ws;                   ws += (size_t)NN * 4;
  int*   rankb = (int*)ws;                   ws += (size_t)NE * 4;        // 1 MB
  float* vbuf  = (float*)ws;                                              // 42 MB

  hipMemsetAsync(z, 0, (size_t)NN * 4, stream);
  hipMemsetAsync(cnt, 0, (size_t)NN * 4, stream);

  node_qq_kernel<<<NN * 4 / 256, 256, 0, stream>>>(f, Wq0, Wq1, Wd00, Wd11, fck_w2, qq);
  hist_kernel<<<NE / 256, 256, 0, stream>>>(ei, cnt);
  scan_kernel<<<1, 1024, 0, stream>>>(cnt, startb, off);
  scatter_kernel<<<NE / 256, 256, 0, stream>>>(ei, off, rankb);
  k_pass_kernel<<<NE / 256, 256, 0, stream>>>(ei, elen, esh, emb, fck_w1, qq, expv, z);
  v_pass_kernel<<<NE / 256, 256, 0, stream>>>(ei, esh, emb, fcv_w1, fcv_w2, f,
                                              expv, z, rankb, vbuf);
  gather_kernel<<<NN / 4, 256, 0, stream>>>(vbuf, startb, cnt, out);
}

// Round 5
// 229.075 us; speedup vs baseline: 3.4033x; 1.0873x over previous
//
#include <hip/hip_runtime.h>
#include <hip/hip_bf16.h>
#include <math.h>

namespace {
constexpr int NN  = 16384;
constexpr int NE  = 262144;
constexpr int DIM = 40;

constexpr float INV_SQRT3   = 0.5773502691896258f;
constexpr float A_PATH      = 0.2041241452319315f;      // 1/sqrt(24)
constexpr float INV_SQRT_NB = 0.31622776601683794f;     // 1/sqrt(10)
constexpr float H_SCALE     = 0.25f;                    // 1/sqrt(16)
constexpr float QSC_S       = 0.25f;
constexpr float QV_S        = 0.35355339059327373f;
constexpr float D00_S       = 1.0f / (16.0f * 1.4142135623730951f);
constexpr float D11_S       = 1.0f / (8.0f * 1.7320508075688772f * 1.4142135623730951f);

constexpr int BKP = 392;  // padded k-stride for Bt (bf16)
}

typedef __attribute__((ext_vector_type(8))) short bf16x8;
typedef __attribute__((ext_vector_type(4))) float f32x4;

static __device__ inline short f2bf(float x) {
  __hip_bfloat16 h = __float2bfloat16(x);
  return __builtin_bit_cast(short, h);
}
static __device__ inline float bf2f(short b) {
  unsigned u = ((unsigned)(unsigned short)b) << 16;
  return __builtin_bit_cast(float, u);
}

// ---------------------------------------------------------------------------
// node_qq: per-node score factorization (round-2 verified)
// ---------------------------------------------------------------------------
__global__ __launch_bounds__(256) void node_qq_kernel(
    const float* __restrict__ f,
    const float* __restrict__ Wq0, const float* __restrict__ Wq1,
    const float* __restrict__ Wd00, const float* __restrict__ Wd11,
    const float* __restrict__ w2k,
    float* __restrict__ qq)
{
  const int gid = blockIdx.x * 256 + threadIdx.x;
  const int n = gid >> 2, rq = gid & 3;

  float fs[16], fv[8][3];
  {
    const float4* fn4 = reinterpret_cast<const float4*>(f + (size_t)n * DIM);
#pragma unroll
    for (int i = 0; i < 10; i++) {
      float4 t = fn4[i];
      int base = i * 4;
#pragma unroll
      for (int k = 0; k < 4; k++) {
        float v = (k == 0) ? t.x : (k == 1) ? t.y : (k == 2) ? t.z : t.w;
        int idx = base + k;
        if (idx < 16) fs[idx] = v;
        else { int r = idx - 16; fv[r / 3][r % 3] = v; }
      }
    }
  }

  float qd0[16];
  {
    float qsc[16];
#pragma unroll
    for (int o = 0; o < 16; o++) {
      float a = 0.f;
#pragma unroll
      for (int i = 0; i < 16; i++) a += fs[i] * Wq0[i * 16 + o];
      qsc[o] = a * QSC_S;
    }
#pragma unroll
    for (int j = 0; j < 16; j++) {
      float a = 0.f;
#pragma unroll
      for (int i = 0; i < 16; i++) a += qsc[i] * Wd00[i * 16 + j];
      qd0[j] = a * D00_S;
    }
  }
  float qdv[8][3];
  {
    float qv[8][3];
#pragma unroll
    for (int o = 0; o < 8; o++)
#pragma unroll
      for (int c = 0; c < 3; c++) {
        float a = 0.f;
#pragma unroll
        for (int i = 0; i < 8; i++) a += fv[i][c] * Wq1[i * 8 + o];
        qv[o][c] = a * QV_S;
      }
#pragma unroll
    for (int j = 0; j < 8; j++)
#pragma unroll
      for (int c = 0; c < 3; c++) {
        float a = 0.f;
#pragma unroll
        for (int i = 0; i < 8; i++) a += qv[i][c] * Wd11[i * 8 + j];
        qdv[j][c] = a * D11_S;
      }
  }

#pragma unroll 1
  for (int rr = 0; rr < 4; rr++) {
    const int r = rq * 4 + rr;
    const float4* __restrict__ w4 = reinterpret_cast<const float4*>(w2k + (size_t)r * 576);
    float q0 = 0.f, qc0 = 0.f, qc1 = 0.f, qc2 = 0.f;

#pragma unroll
    for (int i = 0; i < 16; i++) {
      float t = 0.f;
#pragma unroll
      for (int o4 = 0; o4 < 4; o4++) {
        float4 w = w4[i * 4 + o4];
        t += qd0[o4 * 4 + 0] * w.x + qd0[o4 * 4 + 1] * w.y
           + qd0[o4 * 4 + 2] * w.z + qd0[o4 * 4 + 3] * w.w;
      }
      q0 += fs[i] * t;
    }
#pragma unroll
    for (int i = 0; i < 8; i++) {
      float t = 0.f;
#pragma unroll
      for (int o4 = 0; o4 < 4; o4++) {
        float4 w = w4[64 + i * 4 + o4];
        t += qd0[o4 * 4 + 0] * w.x + qd0[o4 * 4 + 1] * w.y
           + qd0[o4 * 4 + 2] * w.z + qd0[o4 * 4 + 3] * w.w;
      }
      t *= INV_SQRT3;
      qc0 += fv[i][0] * t; qc1 += fv[i][1] * t; qc2 += fv[i][2] * t;
    }
#pragma unroll
    for (int i = 0; i < 16; i++) {
      float t0 = 0.f, t1 = 0.f, t2 = 0.f;
#pragma unroll
      for (int o4 = 0; o4 < 2; o4++) {
        float4 w = w4[96 + i * 2 + o4];
#pragma unroll
        for (int k = 0; k < 4; k++) {
          float wk = (k == 0) ? w.x : (k == 1) ? w.y : (k == 2) ? w.z : w.w;
          int o = o4 * 4 + k;
          t0 += qdv[o][0] * wk; t1 += qdv[o][1] * wk; t2 += qdv[o][2] * wk;
        }
      }
      qc0 += fs[i] * t0; qc1 += fs[i] * t1; qc2 += fs[i] * t2;
    }
#pragma unroll
    for (int i = 0; i < 8; i++) {
      float t0 = 0.f, t1 = 0.f, t2 = 0.f;
#pragma unroll
      for (int o4 = 0; o4 < 2; o4++) {
        float4 w = w4[128 + i * 2 + o4];
#pragma unroll
        for (int k = 0; k < 4; k++) {
          float wk = (k == 0) ? w.x : (k == 1) ? w.y : (k == 2) ? w.z : w.w;
          int o = o4 * 4 + k;
          t0 += qdv[o][0] * wk; t1 += qdv[o][1] * wk; t2 += qdv[o][2] * wk;
        }
      }
      q0 += fv[i][0] * t0 + fv[i][1] * t1 + fv[i][2] * t2;
    }

    float4 outv = make_float4(A_PATH * q0, A_PATH * qc0, A_PATH * qc1, A_PATH * qc2);
    reinterpret_cast<float4*>(qq + ((size_t)n * 16 + r) * 4)[0] = outv;
  }
}

// ---------------------------------------------------------------------------
// K-pass (round-2 verified)
// ---------------------------------------------------------------------------
__global__ __launch_bounds__(256) void k_pass_kernel(
    const int*   __restrict__ ei,
    const float* __restrict__ elen,
    const float* __restrict__ esh,
    const float* __restrict__ emb,
    const float* __restrict__ w1,
    const float* __restrict__ qq,
    float* __restrict__ expv,
    float* __restrict__ z)
{
  const int e = blockIdx.x * 256 + threadIdx.x;
  const int dst = ei[NE + e];

  float el[10];
  const float2* e2 = reinterpret_cast<const float2*>(emb + (size_t)e * 10);
#pragma unroll
  for (int b = 0; b < 5; b++) { float2 t = e2[b]; el[2 * b] = t.x; el[2 * b + 1] = t.y; }

  float h[16];
#pragma unroll
  for (int j = 0; j < 16; j++) {
    float a = 0.f;
#pragma unroll
    for (int b = 0; b < 10; b++) a += el[b] * w1[b * 16 + j];
    a *= INV_SQRT_NB;
    float sig = 1.0f / (1.0f + __expf(-a));
    h[j] = a * sig * H_SCALE;
  }

  float4 sh4 = reinterpret_cast<const float4*>(esh)[e];
  const float4* q4 = reinterpret_cast<const float4*>(qq + (size_t)dst * 64);
  float s = 0.f;
#pragma unroll
  for (int r = 0; r < 16; r++) {
    float4 qv = q4[r];
    s += h[r] * (sh4.x * qv.x + sh4.y * qv.y + sh4.z * qv.z + sh4.w * qv.w);
  }

  float len = elen[e];
  float x = 10.0f * (1.0f - len * (1.0f / 1.3f));
  float cut = (x > 0.f) ? __expf(-1.0f / x) : 0.f;
  float ev = cut * __expf(s);
  expv[e] = ev;
  atomicAdd(&z[dst], ev);
}

// ---------------------------------------------------------------------------
// Counting sort by dst
// ---------------------------------------------------------------------------
__global__ __launch_bounds__(256) void hist_kernel(const int* __restrict__ ei,
                                                   int* __restrict__ cnt)
{
  const int e = blockIdx.x * 256 + threadIdx.x;
  atomicAdd(&cnt[ei[NE + e]], 1);
}

__global__ __launch_bounds__(1024) void scan_kernel(const int* __restrict__ cnt,
                                                    int* __restrict__ start,
                                                    int* __restrict__ off)
{
  __shared__ int part[1024];
  const int t = threadIdx.x;
  const int base = t * 16;
  int loc[16];
  int s = 0;
#pragma unroll
  for (int k = 0; k < 16; k++) { loc[k] = s; s += cnt[base + k]; }
  part[t] = s;
  __syncthreads();
  for (int d = 1; d < 1024; d <<= 1) {
    int v = (t >= d) ? part[t - d] : 0;
    __syncthreads();
    part[t] += v;
    __syncthreads();
  }
  int excl = (t == 0) ? 0 : part[t - 1];
#pragma unroll
  for (int k = 0; k < 16; k++) {
    int v = excl + loc[k];
    start[base + k] = v;
    off[base + k] = v;
  }
}

__global__ __launch_bounds__(256) void scatter_kernel(const int* __restrict__ ei,
                                                      int* __restrict__ off,
                                                      int* __restrict__ eperm)
{
  const int e = blockIdx.x * 256 + threadIdx.x;
  int rk = atomicAdd(&off[ei[NE + e]], 1);
  eperm[rk] = e;
}

// ---------------------------------------------------------------------------
// prep_B: hi/lo bf16 split planes. Bt[col][kp] hi; Bt[32+col][kp] lo.
// ---------------------------------------------------------------------------
__global__ __launch_bounds__(256) void prep_B_kernel(const float* __restrict__ w2v,
                                                     unsigned short* __restrict__ Bt)
{
  int t = blockIdx.x * 256 + threadIdx.x;   // 32*BKP threads
  int col = t / BKP, kp = t % BKP;
  float val = 0.f;
  if (kp < 384 && col < 24) {
    if (kp < 256) {
      int r = kp >> 4, i = kp & 15;
      if (col < 16) val = A_PATH * w2v[r * 576 + i * 16 + col];
      else          val = A_PATH * w2v[r * 576 + 384 + i * 8 + (col - 16)];
    } else {
      int k2 = kp - 256; int r = k2 >> 3, i = k2 & 7;
      if (col < 16) val = A_PATH * INV_SQRT3 * w2v[r * 576 + 256 + i * 16 + col];
      else          val = A_PATH * w2v[r * 576 + 512 + i * 8 + (col - 16)];
    }
  }
  short hi = f2bf(val);
  short lo = f2bf(val - bf2f(hi));
  Bt[t] = (unsigned short)hi;
  Bt[32 * BKP + t] = (unsigned short)lo;
}

// ---------------------------------------------------------------------------
// V-pass via MFMA, split-precision (hi/lo bf16, 3 MFMAs per product).
// Structure otherwise byte-identical to round 4.
// ---------------------------------------------------------------------------
__global__ __launch_bounds__(256) void v_mfma_kernel(
    const int*   __restrict__ ei,
    const float* __restrict__ esh,
    const float* __restrict__ emb,
    const float* __restrict__ w1,      // fcv_w1
    const float* __restrict__ f,
    const float* __restrict__ expv,
    const float* __restrict__ z,
    const int*   __restrict__ eperm,
    const unsigned short* __restrict__ Bt,
    float* __restrict__ vbuf)
{
  __shared__ float h_s[64][17];
  __shared__ float fsT[16][65];
  __shared__ float fvT[24][65];
  __shared__ float scal[64][5];
  __shared__ __attribute__((aligned(16))) unsigned short BtL[64][BKP];
  __shared__ float rows[64][41];

  const int tid  = threadIdx.x;
  const int base = blockIdx.x * 64;

  // stage Bt (hi+lo planes) -> LDS (50 KB)
  {
    const unsigned* sp = reinterpret_cast<const unsigned*>(Bt);
    unsigned* dp = reinterpret_cast<unsigned*>(&BtL[0][0]);
    for (int i = tid; i < 64 * BKP / 2; i += 256) dp[i] = sp[i];
  }

  const int m = tid & 63;
  const int q = tid >> 6;
  const int e = eperm[base + m];

  if (q == 0) {
    int dn = ei[NE + e];
    float4 sh4 = reinterpret_cast<const float4*>(esh)[e];
    float zz = z[dn]; zz = (zz == 0.f) ? 1.f : zz;
    float ev = expv[e];
    float wgt = sqrtf(fmaxf(ev / zz, 0.f));
    scal[m][0] = sh4.x; scal[m][1] = sh4.y; scal[m][2] = sh4.z; scal[m][3] = sh4.w;
    scal[m][4] = wgt;
  } else if (q == 3) {
    int sn = ei[e];
    const float4* f4 = reinterpret_cast<const float4*>(f + (size_t)sn * DIM);
    float v[40];
#pragma unroll
    for (int i = 0; i < 10; i++) {
      float4 t = f4[i];
      v[4 * i] = t.x; v[4 * i + 1] = t.y; v[4 * i + 2] = t.z; v[4 * i + 3] = t.w;
    }
#pragma unroll
    for (int i = 0; i < 16; i++) fsT[i][m] = v[i];
#pragma unroll
    for (int k = 0; k < 24; k++) fvT[(k % 3) * 8 + (k / 3)][m] = v[16 + k];  // fvT[c*8+i]
  } else {
    // q=1: h[0..7], q=2: h[8..15]
    float el[10];
    const float2* e2 = reinterpret_cast<const float2*>(emb + (size_t)e * 10);
#pragma unroll
    for (int b = 0; b < 5; b++) { float2 t = e2[b]; el[2 * b] = t.x; el[2 * b + 1] = t.y; }
    const int j0 = (q == 1) ? 0 : 8;
#pragma unroll
    for (int jj = 0; jj < 8; jj++) {
      int j = j0 + jj;
      float a = 0.f;
#pragma unroll
      for (int b = 0; b < 10; b++) a += el[b] * w1[b * 16 + j];
      a *= INV_SQRT_NB;
      float sig = 1.0f / (1.0f + __expf(-a));
      h_s[m][j] = a * sig * H_SCALE;
    }
  }
  __syncthreads();

  // ---- MFMA phase: wave w computes its 16-edge M-tile (split precision) ----
  const int w    = tid >> 6;
  const int l    = tid & 63;
  const int row  = l & 15;
  const int kb   = l >> 4;
  const int mrow = w * 16 + row;
  const int col  = l & 15;

  f32x4 pfs0 = {0.f, 0.f, 0.f, 0.f}, pfs1 = {0.f, 0.f, 0.f, 0.f};
  f32x4 pc0_0 = {0.f, 0.f, 0.f, 0.f}, pc0_1 = {0.f, 0.f, 0.f, 0.f}, pc0_2 = {0.f, 0.f, 0.f, 0.f};
  f32x4 pc1_0 = {0.f, 0.f, 0.f, 0.f}, pc1_1 = {0.f, 0.f, 0.f, 0.f}, pc1_2 = {0.f, 0.f, 0.f, 0.f};

  // fs path: K=256, 8 K-steps. k = s*32 + kb*8 + j; r = k>>4, i = k&15.
#pragma unroll
  for (int s = 0; s < 8; s++) {
    const int r  = 2 * s + (kb >> 1);
    const int i0 = (kb & 1) * 8;
    const float hr = h_s[mrow][r];
    bf16x8 ah, al;
#pragma unroll
    for (int j = 0; j < 8; j++) {
      float v = hr * fsT[i0 + j][mrow];
      short hi = f2bf(v);
      ah[j] = hi;
      al[j] = f2bf(v - bf2f(hi));
    }
    const int k0 = s * 32 + kb * 8;
    bf16x8 bh0 = *reinterpret_cast<const bf16x8*>(&BtL[col][k0]);
    bf16x8 bh1 = *reinterpret_cast<const bf16x8*>(&BtL[16 + col][k0]);
    bf16x8 bl0 = *reinterpret_cast<const bf16x8*>(&BtL[32 + col][k0]);
    bf16x8 bl1 = *reinterpret_cast<const bf16x8*>(&BtL[48 + col][k0]);
    pfs0 = __builtin_amdgcn_mfma_f32_16x16x32_bf16(ah, bh0, pfs0, 0, 0, 0);
    pfs0 = __builtin_amdgcn_mfma_f32_16x16x32_bf16(al, bh0, pfs0, 0, 0, 0);
    pfs0 = __builtin_amdgcn_mfma_f32_16x16x32_bf16(ah, bl0, pfs0, 0, 0, 0);
    pfs1 = __builtin_amdgcn_mfma_f32_16x16x32_bf16(ah, bh1, pfs1, 0, 0, 0);
    pfs1 = __builtin_amdgcn_mfma_f32_16x16x32_bf16(al, bh1, pfs1, 0, 0, 0);
    pfs1 = __builtin_amdgcn_mfma_f32_16x16x32_bf16(ah, bl1, pfs1, 0, 0, 0);
  }

  // fv path: K=128 per c, 4 K-steps; r = 4s+kb, i = j.
#pragma unroll
  for (int s = 0; s < 4; s++) {
    const int r = 4 * s + kb;
    const float hr = h_s[mrow][r];
    const int k0 = 256 + s * 32 + kb * 8;
    bf16x8 bh0 = *reinterpret_cast<const bf16x8*>(&BtL[col][k0]);
    bf16x8 bh1 = *reinterpret_cast<const bf16x8*>(&BtL[16 + col][k0]);
    bf16x8 bl0 = *reinterpret_cast<const bf16x8*>(&BtL[32 + col][k0]);
    bf16x8 bl1 = *reinterpret_cast<const bf16x8*>(&BtL[48 + col][k0]);
#pragma unroll
    for (int c = 0; c < 3; c++) {
      bf16x8 ah, al;
#pragma unroll
      for (int j = 0; j < 8; j++) {
        float v = hr * fvT[c * 8 + j][mrow];
        short hi = f2bf(v);
        ah[j] = hi;
        al[j] = f2bf(v - bf2f(hi));
      }
      f32x4* p0 = (c == 0) ? &pc0_0 : (c == 1) ? &pc0_1 : &pc0_2;
      f32x4* p1 = (c == 0) ? &pc1_0 : (c == 1) ? &pc1_1 : &pc1_2;
      *p0 = __builtin_amdgcn_mfma_f32_16x16x32_bf16(ah, bh0, *p0, 0, 0, 0);
      *p0 = __builtin_amdgcn_mfma_f32_16x16x32_bf16(al, bh0, *p0, 0, 0, 0);
      *p0 = __builtin_amdgcn_mfma_f32_16x16x32_bf16(ah, bl0, *p0, 0, 0, 0);
      *p1 = __builtin_amdgcn_mfma_f32_16x16x32_bf16(ah, bh1, *p1, 0, 0, 0);
      *p1 = __builtin_amdgcn_mfma_f32_16x16x32_bf16(al, bh1, *p1, 0, 0, 0);
      *p1 = __builtin_amdgcn_mfma_f32_16x16x32_bf16(ah, bl1, *p1, 0, 0, 0);
    }
  }

  // ---- epilogue: combine with per-edge sh scalars, weighted rows -> LDS ----
#pragma unroll
  for (int j = 0; j < 4; j++) {
    const int me = w * 16 + kb * 4 + j;          // D row = (l>>4)*4 + reg
    const float sh0 = scal[me][0], sh1 = scal[me][1], sh2 = scal[me][2], sh3 = scal[me][3];
    const float wg = scal[me][4];
    float vsc = sh0 * pfs0[j] + sh1 * pc0_0[j] + sh2 * pc0_1[j] + sh3 * pc0_2[j];
    rows[me][col] = wg * vsc;
    if (col < 8) {
      rows[me][16 + col * 3 + 0] = wg * (sh1 * pfs1[j] + sh0 * pc1_0[j]);
      rows[me][16 + col * 3 + 1] = wg * (sh2 * pfs1[j] + sh0 * pc1_1[j]);
      rows[me][16 + col * 3 + 2] = wg * (sh3 * pfs1[j] + sh0 * pc1_2[j]);
    }
  }
  __syncthreads();

  // ---- copy rows to vbuf in sorted-rank order (coalesced) ----
  for (int idx = tid; idx < 64 * DIM; idx += 256) {
    int rr = idx / DIM, dd = idx % DIM;
    vbuf[(size_t)(base + rr) * DIM + dd] = rows[rr][dd];
  }
}

// ---------------------------------------------------------------------------
// Gather (round-2 verified verbatim)
// ---------------------------------------------------------------------------
__global__ __launch_bounds__(256) void gather_kernel(
    const float* __restrict__ vbuf,
    const int* __restrict__ start,
    const int* __restrict__ cnt,
    float* __restrict__ fout)
{
  const int tid = threadIdx.x;
  const int node = blockIdx.x * 4 + (tid >> 6);
  const int lane = tid & 63;
  if (lane >= DIM) return;
  const int s0 = start[node];
  const int c = cnt[node];
  float acc = 0.f;
  for (int j = 0; j < c; j++)
    acc += vbuf[(size_t)(s0 + j) * DIM + lane];
  fout[(size_t)node * DIM + lane] = acc;
}

extern "C" void kernel_launch(void* const* d_in, const int* in_sizes, int n_in,
                              void* d_out, int out_size, void* d_ws, size_t ws_size,
                              hipStream_t stream) {
  const float* f      = (const float*)d_in[0];
  const int*   ei     = (const int*)d_in[1];
  const float* elen   = (const float*)d_in[2];
  const float* esh    = (const float*)d_in[3];
  const float* emb    = (const float*)d_in[4];
  const float* Wq0    = (const float*)d_in[5];
  const float* Wq1    = (const float*)d_in[6];
  const float* fck_w1 = (const float*)d_in[7];
  const float* fck_w2 = (const float*)d_in[8];
  const float* fcv_w1 = (const float*)d_in[9];
  const float* fcv_w2 = (const float*)d_in[10];
  const float* Wd00   = (const float*)d_in[11];
  const float* Wd11   = (const float*)d_in[12];

  float* out = (float*)d_out;

  char* ws = (char*)d_ws;
  float* qq    = (float*)ws;  ws += (size_t)NN * 64 * 4;
  float* z     = (float*)ws;  ws += (size_t)NN * 4;
  float* expv  = (float*)ws;  ws += (size_t)NE * 4;
  int*   cnt   = (int*)ws;    ws += (size_t)NN * 4;
  int*   startb= (int*)ws;    ws += (size_t)NN * 4;
  int*   off   = (int*)ws;    ws += (size_t)NN * 4;
  int*   eperm = (int*)ws;    ws += (size_t)NE * 4;
  unsigned short* Bt = (unsigned short*)ws;  ws += (size_t)64 * BKP * 2;
  ws = (char*)(((size_t)ws + 255) & ~(size_t)255);
  float* vbuf  = (float*)ws;  // NE * DIM * 4 = 42 MB

  hipMemsetAsync(z, 0, (size_t)NN * 4, stream);
  hipMemsetAsync(cnt, 0, (size_t)NN * 4, stream);

  prep_B_kernel<<<32 * BKP / 256, 256, 0, stream>>>(fcv_w2, Bt);
  node_qq_kernel<<<NN * 4 / 256, 256, 0, stream>>>(f, Wq0, Wq1, Wd00, Wd11, fck_w2, qq);
  hist_kernel<<<NE / 256, 256, 0, stream>>>(ei, cnt);
  scan_kernel<<<1, 1024, 0, stream>>>(cnt, startb, off);
  scatter_kernel<<<NE / 256, 256, 0, stream>>>(ei, off, eperm);
  k_pass_kernel<<<NE / 256, 256, 0, stream>>>(ei, elen, esh, emb, fck_w1, qq, expv, z);
  v_mfma_kernel<<<NE / 64, 256, 0, stream>>>(ei, esh, emb, fcv_w1, f, expv, z,
                                             eperm, Bt, vbuf);
  gather_kernel<<<NN / 4, 256, 0, stream>>>(vbuf, startb, cnt, out);
}